// Round 8
// baseline (203.579 us; speedup 1.0000x reference)
//
#include <hip/hip_runtime.h>

// out[t][e] = (W[e][ids[t]] + b[e]) * sqrt(512)
// W: (512, 50257) row-major f32; ids: 32768 int32; out: 32768 x 512 f32.
//
// Round 12: READ RUN-LENGTH 256 B -> 1 KB (the one axis never varied).
// R11's phase-locked read windows still ran at ~2.3 TB/s => the strided-256B
// read stream itself is page-locality-capped (201 KB jumps between segments).
//  - VB=256: bucket = 256 vocab ids; each staged row segment is 1 KB
//    contiguous, issued as 4 back-to-back width-4 DMA ops => 1 KB DRAM runs.
//  - Block = (bucket b, e-chunk of 64 rows): tile 64 x 257 dwords (~65.8 KB,
//    DYNAMIC LDS -> 2 blocks/CU). Pad +1 dword/row: scatter column read
//    tile[lane*257 + vl] hits bank (lane+vl)%32 = 2-way (free, m136); pad is
//    DMA-safe since each 256 B dest lies inside one row.
//  - Scatter: one wave per token; lane = e-offset; ONE ds_read + ONE 256 B
//    contiguous store per token. toks[] in LDS (1 KB), uniform broadcast read.
//  - NB=197 buckets, CAP=256 (mean 167, sigma 13), overflow path kept.

constexpr int VOCAB = 50257;
constexpr int EMB   = 512;
constexpr int NTOK  = 8 * 4096;
constexpr float SCALE = 22.62741699796952f;  // sqrt(512)

constexpr int VB   = 256;                     // vocab ids per bucket
constexpr int NB   = (VOCAB + VB - 1) / VB;   // 197 buckets
constexpr int CAP  = 256;                     // capacity (mean 167, sigma 13)
constexpr int ECH  = 64;                      // e-rows per block
constexpr int RSD  = VB + 1;                  // LDS row stride in dwords (257)
constexpr int SMEM_BYTES = (ECH * RSD + CAP) * 4;   // 66,816 B

// d_ws int layout: counts[NB] | ocount[1] | olist[NTOK] | buckets[NB*CAP]

__global__ __launch_bounds__(256) void build_buckets(
    const int* __restrict__ ids,
    int* __restrict__ counts,
    int* __restrict__ olist,
    int* __restrict__ buckets)
{
    int t = blockIdx.x * 256 + threadIdx.x;
    int id = ids[t];
    int bkt = id >> 8;
    int slot = atomicAdd(&counts[bkt], 1);
    if (slot < CAP) {
        buckets[bkt * CAP + slot] = (t << 8) | (id & 255);
    } else {
        int o = atomicAdd(&counts[NB], 1);
        olist[o] = t;
    }
}

__global__ __launch_bounds__(512) void scatter_main(
    const float* __restrict__ W,
    const float* __restrict__ bias,
    const int*   __restrict__ counts,
    const int*   __restrict__ buckets,
    const int*   __restrict__ olist,
    const int*   __restrict__ ids,
    float*       __restrict__ out)
{
    extern __shared__ float smem[];
    float* tile = smem;                        // 64 x 257 dwords
    int*   toks = (int*)(smem + ECH * RSD);    // 256 ints

    const int bid  = blockIdx.x;
    const int b    = bid >> 3;            // bucket
    const int ec   = bid & 7;             // e-chunk
    const int e0   = ec * ECH;
    const int tid  = threadIdx.x;
    const int lane = tid & 63;
    const int w    = tid >> 6;            // wave id 0..7

    const int vstart = min(b * VB, VOCAB - VB);
    const int vadj   = b * VB - vstart;   // 0 except last bucket (175)

    const int cnt = min(counts[b], CAP);  // block-uniform scalar load
    if (tid < CAP) toks[tid] = buckets[b * CAP + tid];
    const float be = bias[e0 + lane];     // lane <-> e-offset

    // ---- stage: wave w rows [w*8, w*8+8); 4 seq 256 B DMA ops per row ----
    // Address stream per wave: 1 KB contiguous runs (4 segs back-to-back),
    // then one 201 KB jump to the next row.
    #pragma unroll
    for (int p = 0; p < 8; ++p) {
        const int r = w * 8 + p;
        const size_t rowbase = (size_t)(e0 + r) * VOCAB + vstart;
        #pragma unroll
        for (int q = 0; q < 4; ++q) {
            const float* gp = W + rowbase + q * 64 + lane;
            float* lp = &tile[r * RSD + q * 64];     // wave-uniform base
            __builtin_amdgcn_global_load_lds(
                (const __attribute__((address_space(1))) void*)gp,
                (__attribute__((address_space(3))) void*)lp, 4, 0, 0);
        }
    }
    __syncthreads();                      // DMA drained; tile + toks visible

    // ---- scatter: one wave per token; 1 ds_read + 1 contiguous 256 B store ----
    const float* tl   = &tile[lane * RSD];
    float*       outp = out + e0 + lane;
    for (int i = w; i < cnt; i += 8) {
        const int pk = toks[i];           // uniform LDS broadcast
        const int t  = pk >> 8;
        const int vl = (pk & 255) + vadj;
        outp[(size_t)t * EMB] = (tl[vl] + be) * SCALE;
    }

    // ---- overflow fix (expected n == 0): b==0 blocks, each its e-chunk ----
    if (b == 0) {
        int n = counts[NB];
        for (int ww = w; ww < n; ww += 8) {
            int t  = olist[ww];
            int id = ids[t];
            int e  = e0 + lane;
            out[(size_t)t * EMB + e] = (W[(size_t)e * VOCAB + id] + bias[e]) * SCALE;
        }
    }
}

// Fallback (round-1 kernel) if d_ws is too small.
__global__ __launch_bounds__(256) void embed_gather(
    const int*   __restrict__ ids,
    const float* __restrict__ W,
    const float* __restrict__ b,
    float*       __restrict__ out)
{
    int idx4 = blockIdx.x * blockDim.x + threadIdx.x;
    int t    = idx4 >> 7;
    int e    = (idx4 & 127) << 2;
    int id = ids[t];
    float4 bb = *reinterpret_cast<const float4*>(b + e);
    const float* wcol = W + (size_t)id;
    float4 o;
    o.x = (wcol[(size_t)(e + 0) * VOCAB] + bb.x) * SCALE;
    o.y = (wcol[(size_t)(e + 1) * VOCAB] + bb.y) * SCALE;
    o.z = (wcol[(size_t)(e + 2) * VOCAB] + bb.z) * SCALE;
    o.w = (wcol[(size_t)(e + 3) * VOCAB] + bb.w) * SCALE;
    *reinterpret_cast<float4*>(out + (size_t)idx4 * 4) = o;
}

extern "C" void kernel_launch(void* const* d_in, const int* in_sizes, int n_in,
                              void* d_out, int out_size, void* d_ws, size_t ws_size,
                              hipStream_t stream)
{
    const int*   ids  = (const int*)  d_in[0];
    const float* W    = (const float*)d_in[1];
    const float* bias = (const float*)d_in[2];
    float*       out  = (float*)d_out;

    const size_t ws_ints_needed = (size_t)NB + 1 + NTOK + (size_t)NB * CAP;

    if (ws_size >= ws_ints_needed * sizeof(int)) {
        int* counts  = (int*)d_ws;
        int* olist   = counts + NB + 1;
        int* buckets = olist + NTOK;

        hipMemsetAsync(counts, 0, (NB + 1) * sizeof(int), stream);
        build_buckets<<<NTOK / 256, 256, 0, stream>>>(ids, counts, olist, buckets);
        scatter_main<<<NB * 8, 512, SMEM_BYTES, stream>>>(W, bias, counts, buckets,
                                                          olist, ids, out);
    } else {
        constexpr int total4 = NTOK * EMB / 4;
        embed_gather<<<total4 / 256, 256, 0, stream>>>(ids, W, bias, out);
    }
}